// Round 20
// baseline (354.574 us; speedup 1.0000x reference)
//
#include <hip/hip_runtime.h>
#include <hip/hip_bf16.h>
#include <stdint.h>

typedef __attribute__((ext_vector_type(8))) short bfx8;
typedef __attribute__((ext_vector_type(4))) short bfx4;
typedef __attribute__((ext_vector_type(4))) float f32x4;
typedef __attribute__((ext_vector_type(4))) unsigned short us4;

#define SCALE_ATT 0.125f

__device__ __forceinline__ unsigned short f2bf(float f) {
  union { float f; unsigned u; } a; a.f = f;
  unsigned r = a.u + 0x7fffu + ((a.u >> 16) & 1u);
  return (unsigned short)(r >> 16);
}

__device__ __forceinline__ bfx8 ld2x64(const unsigned short* p) {
  bfx4 lo = *(const bfx4*)p;
  bfx4 hi = *(const bfx4*)(p + 4);
  return __builtin_shufflevector(lo, hi, 0, 1, 2, 3, 4, 5, 6, 7);
}

// ---------------- prepass: x f32 -> bf16 ----------------
__global__ __launch_bounds__(256) void cvt_x(const float* __restrict__ x,
                                             unsigned short* __restrict__ xb, int n4) {
  int i = blockIdx.x * blockDim.x + threadIdx.x;
  int stride = gridDim.x * blockDim.x;
  const float4* x4 = (const float4*)x;
  for (; i < n4; i += stride) {
    float4 v = x4[i];
    us4 o;
    o[0] = f2bf(v.x); o[1] = f2bf(v.y); o[2] = f2bf(v.z); o[3] = f2bf(v.w);
    *(us4*)&xb[(size_t)i * 4] = o;
  }
}

// ---------------- prepass: W f32 [K][N] -> packed 16x16x32 MFMA B-fragments ----------------
// (R11 version — verified bit-exact) packed[nt][ks][l][e] = W[k=ks*32+(l>>4)*8+e][n=nt*16+(l&15)]
__global__ __launch_bounds__(256) void cvt_w(const float* __restrict__ W0, const float* __restrict__ W1,
                                             const float* __restrict__ W2, const float* __restrict__ W3,
                                             unsigned short* __restrict__ T0, unsigned short* __restrict__ T1,
                                             unsigned short* __restrict__ T2, unsigned short* __restrict__ T3) {
  const float* W; unsigned short* T;
  switch (blockIdx.z) {
    case 0: W = W0; T = T0; break;
    case 1: W = W1; T = T1; break;
    case 2: W = W2; T = T2; break;
    default: W = W3; T = T3; break;
  }
  __shared__ unsigned short Ts[64][68];   // Ts[n_local][k_local]
  int k0 = blockIdx.x * 64, n0 = blockIdx.y * 64;
  int t = threadIdx.x;
  int lrow = t >> 4, c4 = t & 15;
  #pragma unroll
  for (int i = 0; i < 4; i++) {
    int row = lrow + i * 16;                              // k within tile
    float4 v = *(const float4*)&W[(size_t)(k0 + row) * 1024 + n0 + c4 * 4];
    Ts[c4 * 4 + 0][row] = f2bf(v.x);
    Ts[c4 * 4 + 1][row] = f2bf(v.y);
    Ts[c4 * 4 + 2][row] = f2bf(v.z);
    Ts[c4 * 4 + 3][row] = f2bf(v.w);
  }
  __syncthreads();
  // pack: 8 frags per block (4 nt_l x 2 ks_l), 1KB each
  int f = t >> 5, sub = t & 31;
  int nt_l = f >> 1, ks_l = f & 1;
  size_t base = ((size_t)(((n0 >> 4) + nt_l) * 32 + (k0 >> 5) + ks_l)) * 512;
  #pragma unroll
  for (int i = 0; i < 2; i++) {
    int l = sub * 2 + i;
    int row = nt_l * 16 + (l & 15);
    int col = ks_l * 32 + ((l >> 4) << 3);
    us4 a = *(const us4*)&Ts[row][col];
    us4 b = *(const us4*)&Ts[row][col + 4];
    *(us4*)&T[base + l * 8] = a;
    *(us4*)&T[base + l * 8 + 4] = b;
  }
}

// ---------------- 256x256 GEMM, K=1024: ZERO-LDS, ZERO-BARRIER, register-pipelined ----------------
// R17: A-fragments read directly from linear xb (16 rows x 64B contiguous per frag
// — L1/L2 friendly; 4 waves sharing wm hit the same frag window in L1; XCD swizzle
// keeps the 12 bn-blocks of a bm-panel L2-co-resident). B direct-packed as R11.
// 2-stage register rotation {af,ag,b0} || {af2,ag2,b1}; compiler emits counted
// vmcnt per half. Fragment semantics identical to R16 (swizzle pair canceled) ->
// absmax must stay bit-identical.
#define LOADAG(dst, qm, kel) \
  _Pragma("unroll") for (int mi = 0; mi < 4; ++mi) \
    dst[mi] = *(const bfx8*)&Apw[(size_t)(((qm) * 64 + mi * 16) * 1024) + (kel)];

#define LOADBG(dst, ks) \
  _Pragma("unroll") for (int ni = 0; ni < 4; ++ni) \
    dst[ni] = *(const bfx8*)&Bpw[((size_t)(ni * 32 + (ks))) * 512];

#define MFMA16(rb, a, b) \
  _Pragma("unroll") for (int mi = 0; mi < 4; ++mi) \
    _Pragma("unroll") for (int ni = 0; ni < 4; ++ni) \
      acc[(rb) + mi][ni] = __builtin_amdgcn_mfma_f32_16x16x32_bf16(a[mi], b[ni], acc[(rb) + mi][ni], 0, 0, 0);

template<int MODE>  // 0: bf16 out, 3-way weight select (QKV). 1: f32 out + bias (proj)
__global__ __launch_bounds__(512, 2) void gemm8p(
    const unsigned short* __restrict__ A,
    const unsigned short* __restrict__ Bt0, const unsigned short* __restrict__ Bt1,
    const unsigned short* __restrict__ Bt2,
    unsigned short* __restrict__ O0, unsigned short* __restrict__ O1,
    unsigned short* __restrict__ O2,
    const float* __restrict__ bias, float* __restrict__ OutF, int nby) {
  int tid = threadIdx.x;
  int w = tid >> 6, l = tid & 63;
  int lr = l & 15, lh = l >> 4;
  int wm = w >> 2, wn = w & 3;

  // bijective XCD swizzle (nwg % 8 == 0); consecutive wg share bm -> A-panel L2 reuse
  int cpx = gridDim.x >> 3;
  int o = blockIdx.x;
  int wg = (o & 7) * cpx + (o >> 3);
  int bm = wg / nby, bn = wg % nby;

  const unsigned short* Bt;
  unsigned short* Ob = nullptr;
  int n0;
  if (MODE == 0) {
    int sel = bn >> 2;
    n0 = (bn & 3) * 256;
    Bt = sel == 0 ? Bt0 : (sel == 1 ? Bt1 : Bt2);
    Ob = sel == 0 ? O0 : (sel == 1 ? O1 : O2);
  } else {
    Bt = Bt0;
    n0 = bn * 256;
  }
  int am0 = bm * 256;
  const unsigned short* Apw = A + (size_t)(am0 + wm * 128 + lr) * 1024 + lh * 8;
  const unsigned short* Bpw = Bt + ((size_t)((n0 >> 4) + wn * 4) * 32) * 512 + (size_t)l * 8;

  f32x4 acc[8][4];
  #pragma unroll
  for (int i = 0; i < 8; ++i)
    #pragma unroll
    for (int jj = 0; jj < 4; ++jj) acc[i][jj] = (f32x4){0.f, 0.f, 0.f, 0.f};

  bfx8 af[4], ag[4], af2[4], ag2[4], b0[4], b1[4];

  // prologue: load half 0 of tile 0
  LOADAG(af, 0, 0);  LOADAG(ag, 1, 0);  LOADBG(b0, 0);

  #pragma unroll 1
  for (int t = 0; t < 15; ++t) {
    int kel = t * 64;
    // issue next-half loads, then compute current half
    LOADAG(af2, 0, kel + 32);  LOADAG(ag2, 1, kel + 32);  LOADBG(b1, 2 * t + 1);
    __builtin_amdgcn_s_setprio(1);  MFMA16(0, af, b0);  MFMA16(4, ag, b0);
    __builtin_amdgcn_s_setprio(0);
    // issue next-tile half-0 loads, then compute second half
    LOADAG(af, 0, kel + 64);   LOADAG(ag, 1, kel + 64);  LOADBG(b0, 2 * t + 2);
    __builtin_amdgcn_s_setprio(1);  MFMA16(0, af2, b1);  MFMA16(4, ag2, b1);
    __builtin_amdgcn_s_setprio(0);
  }
  // last tile (t = 15)
  LOADAG(af2, 0, 15 * 64 + 32);  LOADAG(ag2, 1, 15 * 64 + 32);  LOADBG(b1, 31);
  __builtin_amdgcn_s_setprio(1);  MFMA16(0, af, b0);   MFMA16(4, ag, b0);
  __builtin_amdgcn_s_setprio(0);
  __builtin_amdgcn_s_setprio(1);  MFMA16(0, af2, b1);  MFMA16(4, ag2, b1);
  __builtin_amdgcn_s_setprio(0);

  // ---- epilogue
  float bv[4];
  if (MODE == 1) {
    #pragma unroll
    for (int ni = 0; ni < 4; ++ni) bv[ni] = bias[n0 + wn * 64 + ni * 16 + lr];
  }
  #pragma unroll
  for (int mi8 = 0; mi8 < 8; ++mi8)
    #pragma unroll
    for (int ni = 0; ni < 4; ++ni)
      #pragma unroll
      for (int j = 0; j < 4; ++j) {
        int r = am0 + wm * 128 + mi8 * 16 + lh * 4 + j;
        int c = n0 + wn * 64 + ni * 16 + lr;
        if (MODE == 0)
          Ob[(size_t)r * 1024 + c] = f2bf(acc[mi8][ni][j]);
        else
          OutF[(size_t)r * 1024 + c] = acc[mi8][ni][j] + bv[ni];
      }
}

// ---------------- causal attention per (b,h) ----------------
// (R16 — KVBLK=64, launch_bounds(256,4), T5 setprio; measured best)
__global__ __launch_bounds__(256, 4) void attn_kernel(
    const unsigned short* __restrict__ Qb, const unsigned short* __restrict__ Kb,
    const unsigned short* __restrict__ Vb, unsigned short* __restrict__ Ab) {
  __shared__ unsigned short Vt[64][260];    // V^T [d][k], stride 520B = 130dw (2-way, free)
  __shared__ unsigned short Pw[4][16][36];  // per-wave P chunk [16 q][32 k + pad]

  int t = threadIdx.x;
  int w = t >> 6, l = t & 63;
  int lr = l & 15, lh = l >> 4;
  int bh = blockIdx.x;
  size_t rowbase = (size_t)(bh >> 4) * 256 * 1024 + (size_t)(bh & 15) * 64;

  {
    int rr = t >> 3, part = t & 7;
    for (int i = 0; i < 8; i++) {
      int row = i * 32 + rr;
      bfx8 vv = *(const bfx8*)(Vb + rowbase + (size_t)row * 1024 + part * 8);
      #pragma unroll
      for (int e = 0; e < 8; e++) Vt[part * 8 + e][row] = (unsigned short)vv[e];
    }
  }
  __syncthreads();

  for (int qt = 0; qt < 4; qt++) {
    int r0 = qt * 64 + w * 16;
    int rmax = r0 + 15;
    const unsigned short* Qrow = Qb + rowbase + (size_t)(r0 + lr) * 1024 + lh * 8;
    bfx8 aq0 = *(const bfx8*)(Qrow);
    bfx8 aq1 = *(const bfx8*)(Qrow + 32);

    float m[4], lsum[4];
    #pragma unroll
    for (int j = 0; j < 4; j++) { m[j] = -1e30f; lsum[j] = 0.f; }
    f32x4 oc[4];
    #pragma unroll
    for (int ct = 0; ct < 4; ct++) oc[ct] = (f32x4){0.f, 0.f, 0.f, 0.f};

    int nkc = (rmax >> 6) + 1;                  // 64-col tiles
    for (int kc = 0; kc < nkc; kc++) {
      int kbase = kc * 64;
      bool haveB = (kbase + 32) <= rmax;        // wave-uniform
      const unsigned short* Kr = Kb + rowbase + (size_t)(kbase + lr) * 1024 + lh * 8;

      bfx8 k0a = *(const bfx8*)(Kr);
      bfx8 k0b = *(const bfx8*)(Kr + 32);
      bfx8 k1a = *(const bfx8*)(Kr + 16 * 1024);
      bfx8 k1b = *(const bfx8*)(Kr + 16 * 1024 + 32);
      f32x4 s0 = (f32x4){0.f, 0.f, 0.f, 0.f};
      f32x4 s1 = (f32x4){0.f, 0.f, 0.f, 0.f};
      f32x4 s2 = (f32x4){0.f, 0.f, 0.f, 0.f};
      f32x4 s3 = (f32x4){0.f, 0.f, 0.f, 0.f};
      __builtin_amdgcn_s_setprio(1);
      s0 = __builtin_amdgcn_mfma_f32_16x16x32_bf16(aq0, k0a, s0, 0, 0, 0);
      s0 = __builtin_amdgcn_mfma_f32_16x16x32_bf16(aq1, k0b, s0, 0, 0, 0);
      s1 = __builtin_amdgcn_mfma_f32_16x16x32_bf16(aq0, k1a, s1, 0, 0, 0);
      s1 = __builtin_amdgcn_mfma_f32_16x16x32_bf16(aq1, k1b, s1, 0, 0, 0);
      __builtin_amdgcn_s_setprio(0);
      if (haveB) {
        bfx8 k2a = *(const bfx8*)(Kr + 32 * 1024);
        bfx8 k2b = *(const bfx8*)(Kr + 32 * 1024 + 32);
        bfx8 k3a = *(const bfx8*)(Kr + 48 * 1024);
        bfx8 k3b = *(const bfx8*)(Kr + 48 * 1024 + 32);
        __builtin_amdgcn_s_setprio(1);
        s2 = __builtin_amdgcn_mfma_f32_16x16x32_bf16(aq0, k2a, s2, 0, 0, 0);
        s2 = __builtin_amdgcn_mfma_f32_16x16x32_bf16(aq1, k2b, s2, 0, 0, 0);
        s3 = __builtin_amdgcn_mfma_f32_16x16x32_bf16(aq0, k3a, s3, 0, 0, 0);
        s3 = __builtin_amdgcn_mfma_f32_16x16x32_bf16(aq1, k3b, s3, 0, 0, 0);
        __builtin_amdgcn_s_setprio(0);
      }

      int c0 = kbase + lr, c1 = c0 + 16, c2 = c0 + 32, c3 = c0 + 48;
      unsigned pb[4];
      #pragma unroll
      for (int j = 0; j < 4; j++) {
        int row = r0 + lh * 4 + j;
        float v0 = (c0 <= row) ? s0[j] : -1e30f;
        float v1 = (c1 <= row) ? s1[j] : -1e30f;
        float v2 = (c2 <= row) ? s2[j] : -1e30f;
        float v3 = (c3 <= row) ? s3[j] : -1e30f;
        float cm = fmaxf(fmaxf(v0, v1), fmaxf(v2, v3));
        cm = fmaxf(cm, __shfl_xor(cm, 1));
        cm = fmaxf(cm, __shfl_xor(cm, 2));
        cm = fmaxf(cm, __shfl_xor(cm, 4));
        cm = fmaxf(cm, __shfl_xor(cm, 8));
        float mn = fmaxf(m[j], cm);
        float sc = __expf((m[j] - mn) * SCALE_ATT);
        float p0 = (c0 <= row) ? __expf((s0[j] - mn) * SCALE_ATT) : 0.f;
        float p1 = (c1 <= row) ? __expf((s1[j] - mn) * SCALE_ATT) : 0.f;
        float p2 = (c2 <= row) ? __expf((s2[j] - mn) * SCALE_ATT) : 0.f;
        float p3 = (c3 <= row) ? __expf((s3[j] - mn) * SCALE_ATT) : 0.f;
        m[j] = mn;
        float cs = (p0 + p1) + (p2 + p3);
        cs += __shfl_xor(cs, 1);
        cs += __shfl_xor(cs, 2);
        cs += __shfl_xor(cs, 4);
        cs += __shfl_xor(cs, 8);
        lsum[j] = lsum[j] * sc + cs;
        #pragma unroll
        for (int ct = 0; ct < 4; ct++) oc[ct][j] *= sc;
        Pw[w][lh * 4 + j][lr] = f2bf(p0);
        Pw[w][lh * 4 + j][16 + lr] = f2bf(p1);
        pb[j] = (unsigned)f2bf(p2) | ((unsigned)f2bf(p3) << 16);
      }

      {
        bfx8 pa = ld2x64(&Pw[w][lr][lh * 8]);
        __builtin_amdgcn_s_setprio(1);
        #pragma unroll
        for (int ct = 0; ct < 4; ct++) {
          bfx8 vb = ld2x64(&Vt[ct * 16 + lr][kbase + lh * 8]);
          oc[ct] = __builtin_amdgcn_mfma_f32_16x16x32_bf16(pa, vb, oc[ct], 0, 0, 0);
        }
        __builtin_amdgcn_s_setprio(0);
      }
      if (haveB) {
        #pragma unroll
        for (int j = 0; j < 4; j++) {
          Pw[w][lh * 4 + j][lr] = (unsigned short)(pb[j] & 0xffffu);
          Pw[w][lh * 4 + j][16 + lr] = (unsigned short)(pb[j] >> 16);
        }
        bfx8 pa = ld2x64(&Pw[w][lr][lh * 8]);
        __builtin_amdgcn_s_setprio(1);
        #pragma unroll
        for (int ct = 0; ct < 4; ct++) {
          bfx8 vb = ld2x64(&Vt[ct * 16 + lr][kbase + 32 + lh * 8]);
          oc[ct] = __builtin_amdgcn_mfma_f32_16x16x32_bf16(pa, vb, oc[ct], 0, 0, 0);
        }
        __builtin_amdgcn_s_setprio(0);
      }
    }

    float rinv[4];
    #pragma unroll
    for (int j = 0; j < 4; j++) rinv[j] = 1.0f / lsum[j];
    #pragma unroll
    for (int ct = 0; ct < 4; ct++)
      #pragma unroll
      for (int j = 0; j < 4; j++) {
        int row = r0 + lh * 4 + j;
        Ab[rowbase + (size_t)row * 1024 + ct * 16 + lr] = f2bf(oc[ct][j] * rinv[j]);
      }
  }
}

extern "C" void kernel_launch(void* const* d_in, const int* in_sizes, int n_in,
                              void* d_out, int out_size, void* d_ws, size_t ws_size,
                              hipStream_t stream) {
  const float* x  = (const float*)d_in[0];
  const float* Wq = (const float*)d_in[1];
  const float* Wk = (const float*)d_in[2];
  const float* Wv = (const float*)d_in[3];
  const float* Wo = (const float*)d_in[4];
  const float* bo = (const float*)d_in[5];
  float* out = (float*)d_out;

  char* ws = (char*)d_ws;
  unsigned short* xb  = (unsigned short*)(ws);                          // 32MB (reused as Ab)
  unsigned short* Wtq = (unsigned short*)(ws + (size_t)(32u << 20));    // 2MB packed
  unsigned short* Wtk = (unsigned short*)(ws + (size_t)(34u << 20));
  unsigned short* Wtv = (unsigned short*)(ws + (size_t)(36u << 20));
  unsigned short* Wto = (unsigned short*)(ws + (size_t)(38u << 20));
  unsigned short* Qb  = (unsigned short*)(ws + (size_t)(40u << 20));    // 32MB
  unsigned short* Kb  = (unsigned short*)(ws + (size_t)(72u << 20));    // 32MB
  unsigned short* Vb  = (unsigned short*)(ws + (size_t)(104u << 20));   // 32MB
  unsigned short* Ab  = xb;  // x dead after gemm_qkv

  cvt_x<<<2048, 256, 0, stream>>>(x, xb, 4194304);
  cvt_w<<<dim3(16, 16, 4), 256, 0, stream>>>(Wq, Wk, Wv, Wo, Wtq, Wtk, Wtv, Wto);
  gemm8p<0><<<768, 512, 0, stream>>>(xb, Wtq, Wtk, Wtv, Qb, Kb, Vb, nullptr, nullptr, 12);
  attn_kernel<<<1024, 256, 0, stream>>>(Qb, Kb, Vb, Ab);
  gemm8p<1><<<256, 512, 0, stream>>>(Ab, Wto, Wto, Wto, nullptr, nullptr, nullptr, bo, out, 4);
}

// Round 21
// 207.308 us; speedup vs baseline: 1.7104x; 1.7104x over previous
//
#include <hip/hip_runtime.h>
#include <hip/hip_bf16.h>
#include <stdint.h>

typedef __attribute__((ext_vector_type(8))) short bfx8;
typedef __attribute__((ext_vector_type(4))) short bfx4;
typedef __attribute__((ext_vector_type(4))) float f32x4;
typedef __attribute__((ext_vector_type(4))) unsigned short us4;

#define SCALE_ATT 0.125f

__device__ __forceinline__ unsigned short f2bf(float f) {
  union { float f; unsigned u; } a; a.f = f;
  unsigned r = a.u + 0x7fffu + ((a.u >> 16) & 1u);
  return (unsigned short)(r >> 16);
}

__device__ __forceinline__ void gll16(const void* g, void* l) {
  __builtin_amdgcn_global_load_lds(
      (__attribute__((address_space(1))) void*)(g),
      (__attribute__((address_space(3))) void*)(l), 16, 0, 0);
}

__device__ __forceinline__ bfx8 ld2x64(const unsigned short* p) {
  bfx4 lo = *(const bfx4*)p;
  bfx4 hi = *(const bfx4*)(p + 4);
  return __builtin_shufflevector(lo, hi, 0, 1, 2, 3, 4, 5, 6, 7);
}

// ---------------- prepass: x f32 -> bf16 ----------------
__global__ __launch_bounds__(256) void cvt_x(const float* __restrict__ x,
                                             unsigned short* __restrict__ xb, int n4) {
  int i = blockIdx.x * blockDim.x + threadIdx.x;
  int stride = gridDim.x * blockDim.x;
  const float4* x4 = (const float4*)x;
  for (; i < n4; i += stride) {
    float4 v = x4[i];
    us4 o;
    o[0] = f2bf(v.x); o[1] = f2bf(v.y); o[2] = f2bf(v.z); o[3] = f2bf(v.w);
    *(us4*)&xb[(size_t)i * 4] = o;
  }
}

// ---------------- prepass: W f32 [K][N] -> packed 16x16x32 MFMA B-fragments ----------------
// (R11 version — verified bit-exact) packed[nt][ks][l][e] = W[k=ks*32+(l>>4)*8+e][n=nt*16+(l&15)]
__global__ __launch_bounds__(256) void cvt_w(const float* __restrict__ W0, const float* __restrict__ W1,
                                             const float* __restrict__ W2, const float* __restrict__ W3,
                                             unsigned short* __restrict__ T0, unsigned short* __restrict__ T1,
                                             unsigned short* __restrict__ T2, unsigned short* __restrict__ T3) {
  const float* W; unsigned short* T;
  switch (blockIdx.z) {
    case 0: W = W0; T = T0; break;
    case 1: W = W1; T = T1; break;
    case 2: W = W2; T = T2; break;
    default: W = W3; T = T3; break;
  }
  __shared__ unsigned short Ts[64][68];   // Ts[n_local][k_local]
  int k0 = blockIdx.x * 64, n0 = blockIdx.y * 64;
  int t = threadIdx.x;
  int lrow = t >> 4, c4 = t & 15;
  #pragma unroll
  for (int i = 0; i < 4; i++) {
    int row = lrow + i * 16;                              // k within tile
    float4 v = *(const float4*)&W[(size_t)(k0 + row) * 1024 + n0 + c4 * 4];
    Ts[c4 * 4 + 0][row] = f2bf(v.x);
    Ts[c4 * 4 + 1][row] = f2bf(v.y);
    Ts[c4 * 4 + 2][row] = f2bf(v.z);
    Ts[c4 * 4 + 3][row] = f2bf(v.w);
  }
  __syncthreads();
  // pack: 8 frags per block (4 nt_l x 2 ks_l), 1KB each
  int f = t >> 5, sub = t & 31;
  int nt_l = f >> 1, ks_l = f & 1;
  size_t base = ((size_t)(((n0 >> 4) + nt_l) * 32 + (k0 >> 5) + ks_l)) * 512;
  #pragma unroll
  for (int i = 0; i < 2; i++) {
    int l = sub * 2 + i;
    int row = nt_l * 16 + (l & 15);
    int col = ks_l * 32 + ((l >> 4) << 3);
    us4 a = *(const us4*)&Ts[row][col];
    us4 b = *(const us4*)&Ts[row][col + 4];
    *(us4*)&T[base + l * 8] = a;
    *(us4*)&T[base + l * 8 + 4] = b;
  }
}

// ---------------- 256x256 GEMM, K=1024, BK=64: A via LDS, B direct-from-global ----------------
// (exact R16 — measured best: qkv 97us, MfmaUtil 46, conflicts 0, total 207us)
#define DS_BAR() __builtin_amdgcn_s_barrier()
#define SB0() __builtin_amdgcn_sched_barrier(0)
#define LGKM(N) do { asm volatile("s_waitcnt lgkmcnt(" #N ")" ::: "memory"); SB0(); } while (0)
#define VMW(N) do { asm volatile("s_waitcnt vmcnt(" #N ")" ::: "memory"); SB0(); } while (0)

#define STAGE(hs, gb, r0, kbyte) do { \
  const char* _g = (const char*)(gb) + (size_t)((r0) + srow) * 2048 + (size_t)(kbyte) + scolb; \
  gll16(_g, (hs) + w * 1024); \
  gll16(_g + 16 * 2048, (hs) + w * 1024 + 512); \
} while (0)

#define LOADA(dst, ptr, qm) \
  _Pragma("unroll") for (int mi = 0; mi < 4; ++mi) \
    dst[mi] = *(const bfx8*)&(ptr)[(wm * 128 + (qm) * 64 + mi * 16 + lr) * 32 + rcol];

#define LOADBG(dst, ks) \
  _Pragma("unroll") for (int ni = 0; ni < 4; ++ni) \
    dst[ni] = *(const bfx8*)&Bpw[((size_t)(ni * 32 + (ks))) * 512];

#define MFMA16(rb, a, b) \
  _Pragma("unroll") for (int mi = 0; mi < 4; ++mi) \
    _Pragma("unroll") for (int ni = 0; ni < 4; ++ni) \
      acc[(rb) + mi][ni] = __builtin_amdgcn_mfma_f32_16x16x32_bf16(a[mi], b[ni], acc[(rb) + mi][ni], 0, 0, 0);

template<int MODE>  // 0: bf16 out, 3-way weight select (QKV). 1: f32 out + bias (proj)
__global__ __launch_bounds__(512, 2) void gemm8p(
    const unsigned short* __restrict__ A,
    const unsigned short* __restrict__ Bt0, const unsigned short* __restrict__ Bt1,
    const unsigned short* __restrict__ Bt2,
    unsigned short* __restrict__ O0, unsigned short* __restrict__ O1,
    unsigned short* __restrict__ O2,
    const float* __restrict__ bias, float* __restrict__ OutF, int nby) {
  __shared__ unsigned short A0s[2][256 * 32];
  __shared__ unsigned short A1s[2][256 * 32];

  int tid = threadIdx.x;
  int w = tid >> 6, l = tid & 63;
  int lr = l & 15, lh = l >> 4;
  int wm = w >> 2, wn = w & 3;
  int srow = w * 32 + (l >> 2);
  int scolb = ((l & 3) * 16) ^ (((l >> 5) & 1) << 5);   // pre-swizzled global col bytes (A)
  int rcol = (lh * 8) ^ (((lr >> 3) & 1) << 4);         // swizzled ds_read col elems (A)

  // bijective XCD swizzle (nwg % 8 == 0)
  int cpx = gridDim.x >> 3;
  int o = blockIdx.x;
  int wg = (o & 7) * cpx + (o >> 3);
  int bm = wg / nby, bn = wg % nby;

  const unsigned short* Bt;
  unsigned short* Ob = nullptr;
  int n0;
  if (MODE == 0) {
    int sel = bn >> 2;
    n0 = (bn & 3) * 256;
    Bt = sel == 0 ? Bt0 : (sel == 1 ? Bt1 : Bt2);
    Ob = sel == 0 ? O0 : (sel == 1 ? O1 : O2);
  } else {
    Bt = Bt0;
    n0 = bn * 256;
  }
  int am0 = bm * 256;
  const unsigned short* Bpw = Bt + ((size_t)((n0 >> 4) + wn * 4) * 32) * 512 + (size_t)l * 8;

  f32x4 acc[8][4];
  #pragma unroll
  for (int i = 0; i < 8; ++i)
    #pragma unroll
    for (int jj = 0; jj < 4; ++jj) acc[i][jj] = (f32x4){0.f, 0.f, 0.f, 0.f};

  bfx8 af[4], ag[4], b0[4], b1[4];

  // prologue: stage A tile0, load B tile0; VMW(8) drains the 4 A-stages
  STAGE(A0s[0], A, am0, 0);   STAGE(A1s[0], A, am0, 64);  SB0();
  LOADBG(b0, 0); SB0();
  LOADBG(b1, 1); SB0();
  VMW(8);
  DS_BAR();

  int cur = 0;
  #pragma unroll 1
  for (int t = 0; t < 15; ++t) {
    int kb = (t + 1) * 128;
    int ks2 = (t + 1) * 2;
    unsigned short* A0c = A0s[cur];       unsigned short* A1c = A1s[cur];
    unsigned short* A0n = A0s[cur ^ 1];   unsigned short* A1n = A1s[cur ^ 1];
    // ---- half 1 (k-slice 0)
    LOADA(af, A0c, 0);  LOADA(ag, A0c, 1);  SB0();
    STAGE(A0n, A, am0, kb);  STAGE(A1n, A, am0, kb + 64);  SB0();
    LGKM(4); VMW(8);                        // af ready; b0 ready
    __builtin_amdgcn_s_setprio(1);  MFMA16(0, af, b0);
    __builtin_amdgcn_s_setprio(0);
    LGKM(0);
    __builtin_amdgcn_s_setprio(1);  MFMA16(4, ag, b0);
    __builtin_amdgcn_s_setprio(0);
    LOADBG(b0, ks2); SB0();                 // prefetch next tile ks0
    // ---- half 2 (k-slice 1)
    LOADA(af, A1c, 0);  LOADA(ag, A1c, 1);  SB0();
    LGKM(4); VMW(8);                        // af ready; b1 ready
    __builtin_amdgcn_s_setprio(1);  MFMA16(0, af, b1);
    __builtin_amdgcn_s_setprio(0);
    LGKM(0);
    __builtin_amdgcn_s_setprio(1);  MFMA16(4, ag, b1);
    __builtin_amdgcn_s_setprio(0);
    LOADBG(b1, ks2 + 1); SB0();             // prefetch next tile ks1
    VMW(8);                                 // drain A stages; B(t+1) stays in flight
    DS_BAR();
    cur ^= 1;
  }
  // ---- last tile (cur==1): no staging, no prefetch
  LOADA(af, A0s[1], 0);  LOADA(ag, A0s[1], 1);  SB0();
  LGKM(4); VMW(4);                          // b0 ready
  __builtin_amdgcn_s_setprio(1);  MFMA16(0, af, b0);
  __builtin_amdgcn_s_setprio(0);
  LGKM(0);
  __builtin_amdgcn_s_setprio(1);  MFMA16(4, ag, b0);
  __builtin_amdgcn_s_setprio(0);
  LOADA(af, A1s[1], 0);  LOADA(ag, A1s[1], 1);  SB0();
  LGKM(4); VMW(0);                          // b1 ready
  __builtin_amdgcn_s_setprio(1);  MFMA16(0, af, b1);
  __builtin_amdgcn_s_setprio(0);
  LGKM(0);
  __builtin_amdgcn_s_setprio(1);  MFMA16(4, ag, b1);
  __builtin_amdgcn_s_setprio(0);

  // ---- epilogue
  float bv[4];
  if (MODE == 1) {
    #pragma unroll
    for (int ni = 0; ni < 4; ++ni) bv[ni] = bias[n0 + wn * 64 + ni * 16 + lr];
  }
  #pragma unroll
  for (int mi8 = 0; mi8 < 8; ++mi8)
    #pragma unroll
    for (int ni = 0; ni < 4; ++ni)
      #pragma unroll
      for (int j = 0; j < 4; ++j) {
        int r = am0 + wm * 128 + mi8 * 16 + lh * 4 + j;
        int c = n0 + wn * 64 + ni * 16 + lr;
        if (MODE == 0)
          Ob[(size_t)r * 1024 + c] = f2bf(acc[mi8][ni][j]);
        else
          OutF[(size_t)r * 1024 + c] = acc[mi8][ni][j] + bv[ni];
      }
}

// ---------------- causal attention per (b,h) ----------------
// (R16 — KVBLK=64, launch_bounds(256,4), T5 setprio; measured best)
__global__ __launch_bounds__(256, 4) void attn_kernel(
    const unsigned short* __restrict__ Qb, const unsigned short* __restrict__ Kb,
    const unsigned short* __restrict__ Vb, unsigned short* __restrict__ Ab) {
  __shared__ unsigned short Vt[64][260];    // V^T [d][k], stride 520B = 130dw (2-way, free)
  __shared__ unsigned short Pw[4][16][36];  // per-wave P chunk [16 q][32 k + pad]

  int t = threadIdx.x;
  int w = t >> 6, l = t & 63;
  int lr = l & 15, lh = l >> 4;
  int bh = blockIdx.x;
  size_t rowbase = (size_t)(bh >> 4) * 256 * 1024 + (size_t)(bh & 15) * 64;

  {
    int rr = t >> 3, part = t & 7;
    for (int i = 0; i < 8; i++) {
      int row = i * 32 + rr;
      bfx8 vv = *(const bfx8*)(Vb + rowbase + (size_t)row * 1024 + part * 8);
      #pragma unroll
      for (int e = 0; e < 8; e++) Vt[part * 8 + e][row] = (unsigned short)vv[e];
    }
  }
  __syncthreads();

  for (int qt = 0; qt < 4; qt++) {
    int r0 = qt * 64 + w * 16;
    int rmax = r0 + 15;
    const unsigned short* Qrow = Qb + rowbase + (size_t)(r0 + lr) * 1024 + lh * 8;
    bfx8 aq0 = *(const bfx8*)(Qrow);
    bfx8 aq1 = *(const bfx8*)(Qrow + 32);

    float m[4], lsum[4];
    #pragma unroll
    for (int j = 0; j < 4; j++) { m[j] = -1e30f; lsum[j] = 0.f; }
    f32x4 oc[4];
    #pragma unroll
    for (int ct = 0; ct < 4; ct++) oc[ct] = (f32x4){0.f, 0.f, 0.f, 0.f};

    int nkc = (rmax >> 6) + 1;                  // 64-col tiles
    for (int kc = 0; kc < nkc; kc++) {
      int kbase = kc * 64;
      bool haveB = (kbase + 32) <= rmax;        // wave-uniform
      const unsigned short* Kr = Kb + rowbase + (size_t)(kbase + lr) * 1024 + lh * 8;

      bfx8 k0a = *(const bfx8*)(Kr);
      bfx8 k0b = *(const bfx8*)(Kr + 32);
      bfx8 k1a = *(const bfx8*)(Kr + 16 * 1024);
      bfx8 k1b = *(const bfx8*)(Kr + 16 * 1024 + 32);
      f32x4 s0 = (f32x4){0.f, 0.f, 0.f, 0.f};
      f32x4 s1 = (f32x4){0.f, 0.f, 0.f, 0.f};
      f32x4 s2 = (f32x4){0.f, 0.f, 0.f, 0.f};
      f32x4 s3 = (f32x4){0.f, 0.f, 0.f, 0.f};
      __builtin_amdgcn_s_setprio(1);
      s0 = __builtin_amdgcn_mfma_f32_16x16x32_bf16(aq0, k0a, s0, 0, 0, 0);
      s0 = __builtin_amdgcn_mfma_f32_16x16x32_bf16(aq1, k0b, s0, 0, 0, 0);
      s1 = __builtin_amdgcn_mfma_f32_16x16x32_bf16(aq0, k1a, s1, 0, 0, 0);
      s1 = __builtin_amdgcn_mfma_f32_16x16x32_bf16(aq1, k1b, s1, 0, 0, 0);
      __builtin_amdgcn_s_setprio(0);
      if (haveB) {
        bfx8 k2a = *(const bfx8*)(Kr + 32 * 1024);
        bfx8 k2b = *(const bfx8*)(Kr + 32 * 1024 + 32);
        bfx8 k3a = *(const bfx8*)(Kr + 48 * 1024);
        bfx8 k3b = *(const bfx8*)(Kr + 48 * 1024 + 32);
        __builtin_amdgcn_s_setprio(1);
        s2 = __builtin_amdgcn_mfma_f32_16x16x32_bf16(aq0, k2a, s2, 0, 0, 0);
        s2 = __builtin_amdgcn_mfma_f32_16x16x32_bf16(aq1, k2b, s2, 0, 0, 0);
        s3 = __builtin_amdgcn_mfma_f32_16x16x32_bf16(aq0, k3a, s3, 0, 0, 0);
        s3 = __builtin_amdgcn_mfma_f32_16x16x32_bf16(aq1, k3b, s3, 0, 0, 0);
        __builtin_amdgcn_s_setprio(0);
      }

      int c0 = kbase + lr, c1 = c0 + 16, c2 = c0 + 32, c3 = c0 + 48;
      unsigned pb[4];
      #pragma unroll
      for (int j = 0; j < 4; j++) {
        int row = r0 + lh * 4 + j;
        float v0 = (c0 <= row) ? s0[j] : -1e30f;
        float v1 = (c1 <= row) ? s1[j] : -1e30f;
        float v2 = (c2 <= row) ? s2[j] : -1e30f;
        float v3 = (c3 <= row) ? s3[j] : -1e30f;
        float cm = fmaxf(fmaxf(v0, v1), fmaxf(v2, v3));
        cm = fmaxf(cm, __shfl_xor(cm, 1));
        cm = fmaxf(cm, __shfl_xor(cm, 2));
        cm = fmaxf(cm, __shfl_xor(cm, 4));
        cm = fmaxf(cm, __shfl_xor(cm, 8));
        float mn = fmaxf(m[j], cm);
        float sc = __expf((m[j] - mn) * SCALE_ATT);
        float p0 = (c0 <= row) ? __expf((s0[j] - mn) * SCALE_ATT) : 0.f;
        float p1 = (c1 <= row) ? __expf((s1[j] - mn) * SCALE_ATT) : 0.f;
        float p2 = (c2 <= row) ? __expf((s2[j] - mn) * SCALE_ATT) : 0.f;
        float p3 = (c3 <= row) ? __expf((s3[j] - mn) * SCALE_ATT) : 0.f;
        m[j] = mn;
        float cs = (p0 + p1) + (p2 + p3);
        cs += __shfl_xor(cs, 1);
        cs += __shfl_xor(cs, 2);
        cs += __shfl_xor(cs, 4);
        cs += __shfl_xor(cs, 8);
        lsum[j] = lsum[j] * sc + cs;
        #pragma unroll
        for (int ct = 0; ct < 4; ct++) oc[ct][j] *= sc;
        Pw[w][lh * 4 + j][lr] = f2bf(p0);
        Pw[w][lh * 4 + j][16 + lr] = f2bf(p1);
        pb[j] = (unsigned)f2bf(p2) | ((unsigned)f2bf(p3) << 16);
      }

      {
        bfx8 pa = ld2x64(&Pw[w][lr][lh * 8]);
        __builtin_amdgcn_s_setprio(1);
        #pragma unroll
        for (int ct = 0; ct < 4; ct++) {
          bfx8 vb = ld2x64(&Vt[ct * 16 + lr][kbase + lh * 8]);
          oc[ct] = __builtin_amdgcn_mfma_f32_16x16x32_bf16(pa, vb, oc[ct], 0, 0, 0);
        }
        __builtin_amdgcn_s_setprio(0);
      }
      if (haveB) {
        #pragma unroll
        for (int j = 0; j < 4; j++) {
          Pw[w][lh * 4 + j][lr] = (unsigned short)(pb[j] & 0xffffu);
          Pw[w][lh * 4 + j][16 + lr] = (unsigned short)(pb[j] >> 16);
        }
        bfx8 pa = ld2x64(&Pw[w][lr][lh * 8]);
        __builtin_amdgcn_s_setprio(1);
        #pragma unroll
        for (int ct = 0; ct < 4; ct++) {
          bfx8 vb = ld2x64(&Vt[ct * 16 + lr][kbase + 32 + lh * 8]);
          oc[ct] = __builtin_amdgcn_mfma_f32_16x16x32_bf16(pa, vb, oc[ct], 0, 0, 0);
        }
        __builtin_amdgcn_s_setprio(0);
      }
    }

    float rinv[4];
    #pragma unroll
    for (int j = 0; j < 4; j++) rinv[j] = 1.0f / lsum[j];
    #pragma unroll
    for (int ct = 0; ct < 4; ct++)
      #pragma unroll
      for (int j = 0; j < 4; j++) {
        int row = r0 + lh * 4 + j;
        Ab[rowbase + (size_t)row * 1024 + ct * 16 + lr] = f2bf(oc[ct][j] * rinv[j]);
      }
  }
}

extern "C" void kernel_launch(void* const* d_in, const int* in_sizes, int n_in,
                              void* d_out, int out_size, void* d_ws, size_t ws_size,
                              hipStream_t stream) {
  const float* x  = (const float*)d_in[0];
  const float* Wq = (const float*)d_in[1];
  const float* Wk = (const float*)d_in[2];
  const float* Wv = (const float*)d_in[3];
  const float* Wo = (const float*)d_in[4];
  const float* bo = (const float*)d_in[5];
  float* out = (float*)d_out;

  char* ws = (char*)d_ws;
  unsigned short* xb  = (unsigned short*)(ws);                          // 32MB (reused as Ab)
  unsigned short* Wtq = (unsigned short*)(ws + (size_t)(32u << 20));    // 2MB packed
  unsigned short* Wtk = (unsigned short*)(ws + (size_t)(34u << 20));
  unsigned short* Wtv = (unsigned short*)(ws + (size_t)(36u << 20));
  unsigned short* Wto = (unsigned short*)(ws + (size_t)(38u << 20));
  unsigned short* Qb  = (unsigned short*)(ws + (size_t)(40u << 20));    // 32MB
  unsigned short* Kb  = (unsigned short*)(ws + (size_t)(72u << 20));    // 32MB
  unsigned short* Vb  = (unsigned short*)(ws + (size_t)(104u << 20));   // 32MB
  unsigned short* Ab  = xb;  // x dead after gemm_qkv

  cvt_x<<<2048, 256, 0, stream>>>(x, xb, 4194304);
  cvt_w<<<dim3(16, 16, 4), 256, 0, stream>>>(Wq, Wk, Wv, Wo, Wtq, Wtk, Wtv, Wto);
  gemm8p<0><<<768, 512, 0, stream>>>(xb, Wtq, Wtk, Wtv, Qb, Kb, Vb, nullptr, nullptr, 12);
  attn_kernel<<<1024, 256, 0, stream>>>(Qb, Kb, Vb, Ab);
  gemm8p<1><<<256, 512, 0, stream>>>(Ab, Wto, Wto, Wto, nullptr, nullptr, nullptr, bo, out, 4);
}